// Round 4
// baseline (541.278 us; speedup 1.0000x reference)
//
#include <hip/hip_runtime.h>
#include <math.h>

// Problem constants (fixed by setup_inputs)
#define TOKENS 50176   // B*T*H*W = 2*8*56*56
#define NWIN   512     // total windows = B * 256
#define C_DIM  256

typedef __attribute__((ext_vector_type(8))) short short8;
typedef __attribute__((ext_vector_type(4))) float f32x4;

// float -> bf16 with round-to-nearest-even
__device__ __forceinline__ unsigned short f2bf(float f) {
    unsigned int u = __builtin_bit_cast(unsigned int, f);
    u += 0x7fffu + ((u >> 16) & 1);
    return (unsigned short)(u >> 16);
}

// async global->LDS, 16B per lane (global_load_lds_dwordx4)
__device__ __forceinline__ void gll16(const void* g, void* l) {
    __builtin_amdgcn_global_load_lds(
        (const __attribute__((address_space(1))) unsigned int*)g,
        (__attribute__((address_space(3))) unsigned int*)l, 16, 0, 0);
}

// exact-enough GELU: Abramowitz-Stegun 7.1.26 erf (|eps|<=1.5e-7) via
// hardware v_rcp_f32 + v_exp_f32. ~13 VALU ops, branch-free. Replacing
// libm erff dropped FC1 VALUBusy 47.6% -> 10.2% (measured r3).
__device__ __forceinline__ float gelu_exact(float v) {
    float z  = v * 0.70710678118654752f;
    float az = fabsf(z);
    float t  = __builtin_amdgcn_rcpf(1.f + 0.3275911f * az);
    float p  = ((((1.061405429f * t - 1.453152027f) * t + 1.421413741f) * t
                 - 0.284496736f) * t + 0.254829592f) * t;
    float er = 1.f - p * __expf(-az * az);
    er = (z < 0.f) ? -er : er;
    return 0.5f * v * (1.f + er);
}

// Map a window-ordered token index u -> flat (b,t,h,w) index.
// Serves BOTH gather (roll(-)+partition) and scatter (reverse+roll(+)).
__device__ __forceinline__ int win_token_to_flat(int u) {
    int g = u / 98;
    int n = u - g * 98;
    int bb  = g >> 8;
    int rem = g & 255;
    int tb = rem >> 6, hb = (rem >> 3) & 7, wb = rem & 7;
    int dt = n / 49;
    int r2 = n - dt * 49;
    int dh = r2 / 7, dw = r2 - dh * 7;
    int t = tb * 2 + dt, h = hb * 7 + dh, w = wb * 7 + dw;
    int ts = (t + 1) & 7;
    int hs = h + 3; if (hs >= 56) hs -= 56;
    int wsx = w + 3; if (wsx >= 56) wsx -= 56;
    return ((bb * 8 + ts) * 56 + hs) * 56 + wsx;
}

// elementwise fp32 -> bf16 (weights)
__global__ __launch_bounds__(256) void cvt_kernel(
        const float* __restrict__ src, unsigned short* __restrict__ dst, int n) {
    int i = blockIdx.x * 256 + threadIdx.x;
    if (i < n) dst[i] = f2bf(src[i]);
}

// Precompute combined rel-pos bias + shift mask tables:
// bm[cls 8][head 8][row 112][col 112] fp32. cls bits: (tb==3)<<2 | (hb==7)<<1 | (wb==7).
// col >= 98 -> -1e30 (padded K tokens), row >= 98 -> 0 (harmless pad rows).
__global__ __launch_bounds__(256) void bm_kernel(
        const float* __restrict__ rpe, float* __restrict__ bm) {
    int i = blockIdx.x * 256 + threadIdx.x;   // 8*8*112*112 = 802816 exact
    int c  = i % 112;
    int t1 = i / 112;
    int r  = t1 % 112;
    int t2 = t1 / 112;
    int head = t2 & 7;
    int cls  = t2 >> 3;
    float val;
    if (c >= 98) {
        val = -1e30f;
    } else if (r >= 98) {
        val = 0.f;
    } else {
        int dt = r / 49, rr = r - dt * 49, dh = rr / 7, dw = rr - dh * 7;
        int dt2 = c / 49, cc = c - dt2 * 49, dh2 = cc / 7, dw2 = cc - dh2 * 7;
        int rt  = (cls & 4) ? (dt  == 0 ? 1 : 2) : 0;
        int rh  = (cls & 2) ? (dh  <  4 ? 1 : 2) : 0;
        int rw  = (cls & 1) ? (dw  <  4 ? 1 : 2) : 0;
        int rt2 = (cls & 4) ? (dt2 == 0 ? 1 : 2) : 0;
        int rh2 = (cls & 2) ? (dh2 <  4 ? 1 : 2) : 0;
        int rw2 = (cls & 1) ? (dw2 <  4 ? 1 : 2) : 0;
        int reg1 = rt * 9 + rh * 3 + rw, reg2 = rt2 * 9 + rh2 * 3 + rw2;
        int idx = (dt - dt2 + 1) * 169 + (dh - dh2 + 6) * 13 + (dw - dw2 + 6);
        val = rpe[idx * 8 + head] + ((reg1 == reg2) ? 0.f : -100.f);
    }
    bm[i] = val;
}

// LayerNorm over C=256, one wave per token, bf16 output.
// GATHER=true: LN1 + roll + window partition fused (gather).
template<bool GATHER>
__global__ __launch_bounds__(256) void ln_kernel(
        const float* __restrict__ x, const float* __restrict__ w,
        const float* __restrict__ b, unsigned short* __restrict__ out) {
    int token = blockIdx.x * 4 + (threadIdx.x >> 6);
    int lane  = threadIdx.x & 63;
    size_t so = GATHER ? (size_t)win_token_to_flat(token) * C_DIM
                       : (size_t)token * C_DIM;
    const float* src = x + so;
    float v[4];
    float sum = 0.f;
#pragma unroll
    for (int j = 0; j < 4; ++j) { v[j] = src[lane + 64 * j]; sum += v[j]; }
#pragma unroll
    for (int o = 32; o > 0; o >>= 1) sum += __shfl_xor(sum, o, 64);
    float mu = sum * (1.f / 256.f);
    float var = 0.f;
#pragma unroll
    for (int j = 0; j < 4; ++j) { float d = v[j] - mu; var += d * d; }
#pragma unroll
    for (int o = 32; o > 0; o >>= 1) var += __shfl_xor(var, o, 64);
    float rstd = rsqrtf(var * (1.f / 256.f) + 1e-5f);
    unsigned short* dst = out + (size_t)token * C_DIM;
#pragma unroll
    for (int j = 0; j < 4; ++j) {
        int c = lane + 64 * j;
        dst[c] = f2bf((v[j] - mu) * rstd * w[c] + b[c]);
    }
}

// ---------------------------------------------------------------------------
// Barrier-free register-tiled GEMM for thin-K layers (K=256):
// C(MxN) = A(MxK) @ B(NxK)^T. Block = 128x128, wave = 32 rows x 128 cols.
// NO LDS, NO barriers: each wave loads its own A frags (2/step, 64B-coalesced
// per 16 lanes) and B frags (8/step, L2-hot weight panel) straight into
// registers; 16 MFMA/step; K fully unrolled. Waves are independent -> the
// per-K-step barrier+vmcnt(0) serialization of the LDS design (measured
// 70-82us across 3 variants, all pipes <25%) is gone entirely.
// EPI: 0 = +bias, *scale on Q cols (col0<256), bf16 store   (qkv)
//      1 = +bias, scatter via map, +res, fp32               (proj)
//      2 = +bias, exact GELU (fast erf), bf16 store         (fc1)
// ---------------------------------------------------------------------------
template<int EPI, int K>
__global__ __launch_bounds__(256, 2) void rt_gemm(
        const unsigned short* __restrict__ A, const unsigned short* __restrict__ B,
        const float* __restrict__ bias, const float* __restrict__ res,
        void* __restrict__ Cout, int M, int N) {
    int tid = threadIdx.x;
    int wave = tid >> 6, lane = tid & 63;

    // XCD-aware bijective swizzle (all grids here are %8==0):
    // keeps the col-tiles sharing one A row-panel on one XCD's L2.
    int nwg = gridDim.x * gridDim.y;
    int bid = blockIdx.y * gridDim.x + blockIdx.x;
    int swz = (bid & 7) * (nwg >> 3) + (bid >> 3);
    int bx = swz % gridDim.x, by = swz / gridDim.x;

    int row0 = by * 128 + wave * 32;   // wave-private 32 rows
    int col0 = bx * 128;

    int fm = lane & 15, fq = lane >> 4;  // frag row / k-chunk
    const unsigned short* Ap = A + (size_t)(row0 + fm) * K + fq * 8;
    const unsigned short* Bp = B + (size_t)(col0 + fm) * K + fq * 8;

    f32x4 acc[2][8] = {};

#pragma unroll
    for (int kk = 0; kk < K; kk += 32) {
        short8 a0 = *(const short8*)(Ap + kk);
        short8 a1 = *(const short8*)(Ap + (size_t)16 * K + kk);
        short8 bfr[8];
#pragma unroll
        for (int j = 0; j < 8; ++j)
            bfr[j] = *(const short8*)(Bp + (size_t)j * 16 * K + kk);
#pragma unroll
        for (int j = 0; j < 8; ++j) {
            acc[0][j] = __builtin_amdgcn_mfma_f32_16x16x32_bf16(a0, bfr[j], acc[0][j], 0, 0, 0);
            acc[1][j] = __builtin_amdgcn_mfma_f32_16x16x32_bf16(a1, bfr[j], acc[1][j], 0, 0, 0);
        }
    }

    float bj[8];
#pragma unroll
    for (int j = 0; j < 8; ++j) bj[j] = bias[col0 + j * 16 + fm];

    if (EPI == 0) {
        unsigned short* C = (unsigned short*)Cout;
        float mul = (col0 < 256) ? 0.17677669529663687f : 1.f;  // scale Q
#pragma unroll
        for (int i = 0; i < 2; ++i)
#pragma unroll
            for (int v = 0; v < 4; ++v) {
                int r = row0 + i * 16 + fq * 4 + v;
                size_t base = (size_t)r * N + col0 + fm;
#pragma unroll
                for (int j = 0; j < 8; ++j)
                    C[base + j * 16] = f2bf((acc[i][j][v] + bj[j]) * mul);
            }
    } else if (EPI == 1) {
        float* C = (float*)Cout;
#pragma unroll
        for (int i = 0; i < 2; ++i)
#pragma unroll
            for (int v = 0; v < 4; ++v) {
                int r = row0 + i * 16 + fq * 4 + v;
                size_t base = (size_t)win_token_to_flat(r) * C_DIM + col0 + fm;
#pragma unroll
                for (int j = 0; j < 8; ++j)
                    C[base + j * 16] = res[base + j * 16] + acc[i][j][v] + bj[j];
            }
    } else {
        unsigned short* C = (unsigned short*)Cout;
#pragma unroll
        for (int i = 0; i < 2; ++i)
#pragma unroll
            for (int v = 0; v < 4; ++v) {
                int r = row0 + i * 16 + fq * 4 + v;
                size_t base = (size_t)r * N + col0 + fm;
#pragma unroll
                for (int j = 0; j < 8; ++j)
                    C[base + j * 16] = f2bf(gelu_exact(acc[i][j][v] + bj[j]));
            }
    }
}

// bf16 MFMA GEMM for FC2 (K=1024; B-panel too big for the reg-tiled scheme).
// r2 structure (best measured for this layer): double-buffered LDS, ONE
// __syncthreads per K-step, next tile's global_load_lds issued right after
// the barrier. XCD-bijective block swizzle.
// EPI: 3 = +bias, +res in place, fp32 (fc2)
template<int EPI>
__global__ __launch_bounds__(256) void mfma_gemm(
        const unsigned short* __restrict__ A, const unsigned short* __restrict__ B,
        const float* __restrict__ bias, const float* __restrict__ res,
        void* __restrict__ Cout, int M, int N, int K) {
    __shared__ __attribute__((aligned(16))) unsigned short Asm[2][128 * 32];
    __shared__ __attribute__((aligned(16))) unsigned short Bsm[2][128 * 32];
    int tid = threadIdx.x;
    int wave = tid >> 6, lane = tid & 63;

    int nwg = gridDim.x * gridDim.y;
    int bid = blockIdx.y * gridDim.x + blockIdx.x;
    int swz = (bid & 7) * (nwg >> 3) + (bid >> 3);
    int bx = swz % gridDim.x, by = swz / gridDim.x;

    int row0 = by * 128, col0 = bx * 128;
    int wr = (wave >> 1) * 64;
    int wc = (wave & 1) * 64;

    f32x4 acc[4][4] = {};

    int sr = tid >> 2;
    int sk = (tid & 3) * 8;
    const unsigned short* Ag0 = A + (size_t)(row0 + sr) * K + sk;
    const unsigned short* Ag1 = A + (size_t)(row0 + 64 + sr) * K + sk;
    const unsigned short* Bg0 = B + (size_t)(col0 + sr) * K + sk;
    const unsigned short* Bg1 = B + (size_t)(col0 + 64 + sr) * K + sk;
    int loff = tid * 8;

    int fm = lane & 15, fq = lane >> 4;
    int fks = fq * 8;

    // prologue: stage K-tile 0 into buffer 0
    gll16(Ag0, &Asm[0][loff]);
    gll16(Ag1, &Asm[0][loff + 2048]);
    gll16(Bg0, &Bsm[0][loff]);
    gll16(Bg1, &Bsm[0][loff + 2048]);

    int nk = K >> 5;
    for (int s = 0; s < nk; ++s) {
        int cur = s & 1;
        __syncthreads();   // drains vmcnt: buf[cur] staged; buf[cur^1] reads done
        if (s + 1 < nk) {
            int k0 = (s + 1) << 5;
            gll16(Ag0 + k0, &Asm[cur ^ 1][loff]);
            gll16(Ag1 + k0, &Asm[cur ^ 1][loff + 2048]);
            gll16(Bg0 + k0, &Bsm[cur ^ 1][loff]);
            gll16(Bg1 + k0, &Bsm[cur ^ 1][loff + 2048]);
        }
        short8 af[4], bfr[4];
#pragma unroll
        for (int t4 = 0; t4 < 4; ++t4) {
            af[t4]  = *(const short8*)&Asm[cur][(wr + t4 * 16 + fm) * 32 + fks];
            bfr[t4] = *(const short8*)&Bsm[cur][(wc + t4 * 16 + fm) * 32 + fks];
        }
#pragma unroll
        for (int i = 0; i < 4; ++i)
#pragma unroll
            for (int j = 0; j < 4; ++j)
                acc[i][j] = __builtin_amdgcn_mfma_f32_16x16x32_bf16(
                    af[i], bfr[j], acc[i][j], 0, 0, 0);
    }

    int crow0 = row0 + wr + (lane >> 4) * 4;
    int ccol0 = col0 + wc + (lane & 15);
    float bj[4];
#pragma unroll
    for (int j = 0; j < 4; ++j) bj[j] = bias[ccol0 + j * 16];

    {   // EPI == 3: +bias, +res in place, fp32
        float* C = (float*)Cout;
#pragma unroll
        for (int i = 0; i < 4; ++i)
#pragma unroll
            for (int v = 0; v < 4; ++v) {
                size_t base = (size_t)(crow0 + i * 16 + v) * N + ccol0;
#pragma unroll
                for (int j = 0; j < 4; ++j)
                    C[base + j * 16] = res[base + j * 16] + acc[i][j][v] + bj[j];
            }
    }
}

// MFMA windowed attention: one block per (window, head), 4 waves.
// N=98 padded to 112 (7 row-strips of 16). Per strip (owned by one wave):
//   S = Q K^T (7 MFMA, A/B frags direct from global, row-clamped)
//   + bm table, row softmax (16-lane shfl_xor), P -> LDS (C->A layout),
//   O = P V via 8 MFMA against LDS-transposed V, *1/rowsum at store.
// qkv is bf16, Q pre-scaled by 32^-0.5 in the qkv GEMM epilogue.
__global__ __launch_bounds__(256) void attn_mfma_kernel(
        const unsigned short* __restrict__ qkv, const float* __restrict__ bm,
        unsigned short* __restrict__ out) {
    __shared__ __attribute__((aligned(16))) unsigned short Vt[32][136];
    __shared__ __attribute__((aligned(16))) unsigned short Pw[4][16][136];
    int blk = blockIdx.x;
    int g = blk >> 3, head = blk & 7;
    int tid = threadIdx.x, wave = tid >> 6, lane = tid & 63;

    // zero Vt token-pad cols [98,128) (P pad cols are exact 0, need finite V there)
    for (int i = tid; i < 32 * 30; i += 256) {
        int d = i / 30, c = 98 + (i - d * 30);
        Vt[d][c] = 0;
    }
    // stage V_h transposed: Vt[d][token], coalesced global reads
    const unsigned short* vbase = qkv + (size_t)g * 98 * 768 + 512 + head * 32;
    for (int i = tid; i < 98 * 16; i += 256) {
        int n = i >> 4, dp = i & 15;
        unsigned int val = *(const unsigned int*)(vbase + (size_t)n * 768 + dp * 2);
        Vt[dp * 2][n]     = (unsigned short)val;
        Vt[dp * 2 + 1][n] = (unsigned short)(val >> 16);
    }
    // zero per-wave P k-pad cols [112,128) (read by last PV k-step)
    {
        int m = lane >> 2, c = 112 + (lane & 3) * 4;
        *(unsigned long long*)&Pw[wave][m][c] = 0ULL;
    }
    __syncthreads();

    const unsigned short* qbase = qkv + (size_t)g * 98 * 768 + head * 32;
    const unsigned short* kbase = qbase + 256;
    int rem = g & 255;
    int cls = (((rem >> 6) == 3) << 2) | (((((rem >> 3) & 7)) == 7) << 1) | ((rem & 7) == 7);
    const float* bmh = bm + (size_t)(cls * 8 + head) * 112 * 112;

    int fm = lane & 15, fq = lane >> 4;
    int fk = fq * 8;
    unsigned short* obase = out + (size_t)g * 98 * 256 + head * 32;

    for (int s = wave; s < 7; s += 4) {
        int m0 = s * 16;
        int arow = m0 + fm; if (arow > 97) arow = 97;   // clamp pad rows (finite garbage)
        short8 af = *(const short8*)(qbase + (size_t)arow * 768 + fk);
        f32x4 S[7];
        f32x4 z = {0.f, 0.f, 0.f, 0.f};
#pragma unroll
        for (int j = 0; j < 7; ++j) {
            int krow = j * 16 + fm; if (krow > 97) krow = 97;
            short8 kf = *(const short8*)(kbase + (size_t)krow * 768 + fk);
            S[j] = __builtin_amdgcn_mfma_f32_16x16x32_bf16(af, kf, z, 0, 0, 0);
        }
        // + bias/mask table (pad cols get -1e30 -> exp 0)
        const float* bmrow = bmh + (m0 + fq * 4) * 112 + fm;
#pragma unroll
        for (int j = 0; j < 7; ++j)
#pragma unroll
            for (int v = 0; v < 4; ++v)
                S[j][v] += bmrow[v * 112 + j * 16];
        // row softmax: rows live in 16-lane col groups (lane&15), 4 rows/lane (v)
        float inv[4];
#pragma unroll
        for (int v = 0; v < 4; ++v) {
            float m_ = S[0][v];
#pragma unroll
            for (int j = 1; j < 7; ++j) m_ = fmaxf(m_, S[j][v]);
#pragma unroll
            for (int o = 1; o < 16; o <<= 1) m_ = fmaxf(m_, __shfl_xor(m_, o, 64));
            float t = 0.f;
#pragma unroll
            for (int j = 0; j < 7; ++j) { S[j][v] = __expf(S[j][v] - m_); t += S[j][v]; }
#pragma unroll
            for (int o = 1; o < 16; o <<= 1) t += __shfl_xor(t, o, 64);
            inv[v] = 1.f / t;   // applied at output store (PV is linear)
        }
        // P: C-layout -> A-layout via per-wave LDS (same-wave DS ordering, no barrier)
#pragma unroll
        for (int j = 0; j < 7; ++j)
#pragma unroll
            for (int v = 0; v < 4; ++v)
                Pw[wave][fq * 4 + v][j * 16 + fm] = f2bf(S[j][v]);
        // O = P @ V
        f32x4 O0 = {0.f, 0.f, 0.f, 0.f}, O1 = {0.f, 0.f, 0.f, 0.f};
#pragma unroll
        for (int ks = 0; ks < 4; ++ks) {
            short8 pf = *(const short8*)&Pw[wave][fm][ks * 32 + fk];
            short8 v0 = *(const short8*)&Vt[fm][ks * 32 + fk];
            short8 v1 = *(const short8*)&Vt[16 + fm][ks * 32 + fk];
            O0 = __builtin_amdgcn_mfma_f32_16x16x32_bf16(pf, v0, O0, 0, 0, 0);
            O1 = __builtin_amdgcn_mfma_f32_16x16x32_bf16(pf, v1, O1, 0, 0, 0);
        }
#pragma unroll
        for (int v = 0; v < 4; ++v) {
            int row = m0 + fq * 4 + v;
            if (row < 98) {
                obase[(size_t)row * 256 + fm]      = f2bf(O0[v] * inv[v]);
                obase[(size_t)row * 256 + 16 + fm] = f2bf(O1[v] * inv[v]);
            }
        }
    }
}

extern "C" void kernel_launch(void* const* d_in, const int* in_sizes, int n_in,
                              void* d_out, int out_size, void* d_ws, size_t ws_size,
                              hipStream_t stream) {
    const float* x     = (const float*)d_in[0];
    const float* n1w   = (const float*)d_in[1];
    const float* n1b   = (const float*)d_in[2];
    const float* qkvw  = (const float*)d_in[3];
    const float* qkvb  = (const float*)d_in[4];
    const float* projw = (const float*)d_in[5];
    const float* projb = (const float*)d_in[6];
    const float* rpe   = (const float*)d_in[7];
    const float* n2w   = (const float*)d_in[8];
    const float* n2b   = (const float*)d_in[9];
    const float* fc1w  = (const float*)d_in[10];
    const float* fc1b  = (const float*)d_in[11];
    const float* fc2w  = (const float*)d_in[12];
    const float* fc2b  = (const float*)d_in[13];
    float* out = (float*)d_out;

    // workspace layout
    unsigned short* wqkv  = (unsigned short*)d_ws;            // 768*256 bf16
    unsigned short* wproj = wqkv + 768 * 256;                 // 256*256
    unsigned short* wfc1  = wproj + 256 * 256;                // 1024*256
    unsigned short* wfc2  = wfc1 + 1024 * 256;                // 256*1024
    float* bm = (float*)(wfc2 + 256 * 1024);                  // 8*8*112*112 fp32
    unsigned short* actA  = (unsigned short*)(bm + 8 * 8 * 112 * 112); // TOKENS*256 bf16
    unsigned short* attnO = actA + (size_t)TOKENS * 256;      // TOKENS*256 bf16
    unsigned short* qkv_bf = attnO + (size_t)TOKENS * 256;    // TOKENS*768 bf16
    unsigned short* fc1o = qkv_bf;                            // TOKENS*1024 bf16 (aliases dead qkv)

    // 0. bias/mask tables + weight casts
    bm_kernel<<<8 * 8 * 112 * 112 / 256, 256, 0, stream>>>(rpe, bm);
    cvt_kernel<<<(768 * 256 + 255) / 256, 256, 0, stream>>>(qkvw, wqkv, 768 * 256);
    cvt_kernel<<<(256 * 256 + 255) / 256, 256, 0, stream>>>(projw, wproj, 256 * 256);
    cvt_kernel<<<(1024 * 256 + 255) / 256, 256, 0, stream>>>(fc1w, wfc1, 1024 * 256);
    cvt_kernel<<<(256 * 1024 + 255) / 256, 256, 0, stream>>>(fc2w, wfc2, 256 * 1024);

    // 1. LN1 + roll + window partition (gather), bf16 out
    ln_kernel<true><<<TOKENS / 4, 256, 0, stream>>>(x, n1w, n1b, actA);
    // 2. QKV projection -> bf16, Q pre-scaled (reg-tiled, barrier-free)
    rt_gemm<0, 256><<<dim3(768 / 128, TOKENS / 128), 256, 0, stream>>>(
        actA, wqkv, qkvb, nullptr, qkv_bf, TOKENS, 768);
    // 3. MFMA windowed attention -> bf16
    attn_mfma_kernel<<<NWIN * 8, 256, 0, stream>>>(qkv_bf, bm, attnO);
    // 4. proj + window reverse + roll back + residual -> d_out (x1, fp32)
    rt_gemm<1, 256><<<dim3(256 / 128, TOKENS / 128), 256, 0, stream>>>(
        attnO, wproj, projb, x, out, TOKENS, 256);
    // 5. LN2 -> bf16
    ln_kernel<false><<<TOKENS / 4, 256, 0, stream>>>(out, n2w, n2b, actA);
    // 6. FC1 + GELU -> bf16 (aliases dead qkv buffer)
    rt_gemm<2, 256><<<dim3(1024 / 128, TOKENS / 128), 256, 0, stream>>>(
        actA, wfc1, fc1b, nullptr, fc1o, TOKENS, 1024);
    // 7. FC2 + residual (in place on d_out) — LDS r2-structure, K=1024
    mfma_gemm<3><<<dim3(256 / 128, TOKENS / 128), 256, 0, stream>>>(
        fc1o, wfc2, fc2b, out, out, TOKENS, 256, 1024);
}

// Round 5
// 415.565 us; speedup vs baseline: 1.3025x; 1.3025x over previous
//
#include <hip/hip_runtime.h>
#include <math.h>

// Problem constants (fixed by setup_inputs)
#define TOKENS 50176   // B*T*H*W = 2*8*56*56
#define NWIN   512     // total windows = B * 256
#define C_DIM  256

typedef __attribute__((ext_vector_type(8))) short short8;
typedef __attribute__((ext_vector_type(4))) float f32x4;

// float -> bf16 with round-to-nearest-even
__device__ __forceinline__ unsigned short f2bf(float f) {
    unsigned int u = __builtin_bit_cast(unsigned int, f);
    u += 0x7fffu + ((u >> 16) & 1);
    return (unsigned short)(u >> 16);
}

// async global->LDS, 16B per lane (global_load_lds_dwordx4)
__device__ __forceinline__ void gll16(const void* g, void* l) {
    __builtin_amdgcn_global_load_lds(
        (const __attribute__((address_space(1))) unsigned int*)g,
        (__attribute__((address_space(3))) unsigned int*)l, 16, 0, 0);
}

// exact-enough GELU: Abramowitz-Stegun 7.1.26 erf (|eps|<=1.5e-7) via
// hardware v_rcp_f32 + v_exp_f32. ~13 VALU ops, branch-free. Replacing
// libm erff dropped FC1 VALUBusy 47.6% -> 10.2% (measured r3).
__device__ __forceinline__ float gelu_exact(float v) {
    float z  = v * 0.70710678118654752f;
    float az = fabsf(z);
    float t  = __builtin_amdgcn_rcpf(1.f + 0.3275911f * az);
    float p  = ((((1.061405429f * t - 1.453152027f) * t + 1.421413741f) * t
                 - 0.284496736f) * t + 0.254829592f) * t;
    float er = 1.f - p * __expf(-az * az);
    er = (z < 0.f) ? -er : er;
    return 0.5f * v * (1.f + er);
}

// Map a window-ordered token index u -> flat (b,t,h,w) index.
// Serves BOTH gather (roll(-)+partition) and scatter (reverse+roll(+)).
__device__ __forceinline__ int win_token_to_flat(int u) {
    int g = u / 98;
    int n = u - g * 98;
    int bb  = g >> 8;
    int rem = g & 255;
    int tb = rem >> 6, hb = (rem >> 3) & 7, wb = rem & 7;
    int dt = n / 49;
    int r2 = n - dt * 49;
    int dh = r2 / 7, dw = r2 - dh * 7;
    int t = tb * 2 + dt, h = hb * 7 + dh, w = wb * 7 + dw;
    int ts = (t + 1) & 7;
    int hs = h + 3; if (hs >= 56) hs -= 56;
    int wsx = w + 3; if (wsx >= 56) wsx -= 56;
    return ((bb * 8 + ts) * 56 + hs) * 56 + wsx;
}

// elementwise fp32 -> bf16 (weights)
__global__ __launch_bounds__(256) void cvt_kernel(
        const float* __restrict__ src, unsigned short* __restrict__ dst, int n) {
    int i = blockIdx.x * 256 + threadIdx.x;
    if (i < n) dst[i] = f2bf(src[i]);
}

// Precompute combined rel-pos bias + shift mask tables:
// bm[cls 8][head 8][row 112][col 112] fp32. cls bits: (tb==3)<<2 | (hb==7)<<1 | (wb==7).
// col >= 98 -> -1e30 (padded K tokens), row >= 98 -> 0 (harmless pad rows).
__global__ __launch_bounds__(256) void bm_kernel(
        const float* __restrict__ rpe, float* __restrict__ bm) {
    int i = blockIdx.x * 256 + threadIdx.x;   // 8*8*112*112 = 802816 exact
    int c  = i % 112;
    int t1 = i / 112;
    int r  = t1 % 112;
    int t2 = t1 / 112;
    int head = t2 & 7;
    int cls  = t2 >> 3;
    float val;
    if (c >= 98) {
        val = -1e30f;
    } else if (r >= 98) {
        val = 0.f;
    } else {
        int dt = r / 49, rr = r - dt * 49, dh = rr / 7, dw = rr - dh * 7;
        int dt2 = c / 49, cc = c - dt2 * 49, dh2 = cc / 7, dw2 = cc - dh2 * 7;
        int rt  = (cls & 4) ? (dt  == 0 ? 1 : 2) : 0;
        int rh  = (cls & 2) ? (dh  <  4 ? 1 : 2) : 0;
        int rw  = (cls & 1) ? (dw  <  4 ? 1 : 2) : 0;
        int rt2 = (cls & 4) ? (dt2 == 0 ? 1 : 2) : 0;
        int rh2 = (cls & 2) ? (dh2 <  4 ? 1 : 2) : 0;
        int rw2 = (cls & 1) ? (dw2 <  4 ? 1 : 2) : 0;
        int reg1 = rt * 9 + rh * 3 + rw, reg2 = rt2 * 9 + rh2 * 3 + rw2;
        int idx = (dt - dt2 + 1) * 169 + (dh - dh2 + 6) * 13 + (dw - dw2 + 6);
        val = rpe[idx * 8 + head] + ((reg1 == reg2) ? 0.f : -100.f);
    }
    bm[i] = val;
}

// LayerNorm over C=256, one wave per token, bf16 output.
// GATHER=true: LN1 + roll + window partition fused (gather).
template<bool GATHER>
__global__ __launch_bounds__(256) void ln_kernel(
        const float* __restrict__ x, const float* __restrict__ w,
        const float* __restrict__ b, unsigned short* __restrict__ out) {
    int token = blockIdx.x * 4 + (threadIdx.x >> 6);
    int lane  = threadIdx.x & 63;
    size_t so = GATHER ? (size_t)win_token_to_flat(token) * C_DIM
                       : (size_t)token * C_DIM;
    const float* src = x + so;
    float v[4];
    float sum = 0.f;
#pragma unroll
    for (int j = 0; j < 4; ++j) { v[j] = src[lane + 64 * j]; sum += v[j]; }
#pragma unroll
    for (int o = 32; o > 0; o >>= 1) sum += __shfl_xor(sum, o, 64);
    float mu = sum * (1.f / 256.f);
    float var = 0.f;
#pragma unroll
    for (int j = 0; j < 4; ++j) { float d = v[j] - mu; var += d * d; }
#pragma unroll
    for (int o = 32; o > 0; o >>= 1) var += __shfl_xor(var, o, 64);
    float rstd = rsqrtf(var * (1.f / 256.f) + 1e-5f);
    unsigned short* dst = out + (size_t)token * C_DIM;
#pragma unroll
    for (int j = 0; j < 4; ++j) {
        int c = lane + 64 * j;
        dst[c] = f2bf((v[j] - mu) * rstd * w[c] + b[c]);
    }
}

// bf16 MFMA GEMM: C(MxN) = A(MxK) @ B(NxK)^T.
// v5 structure: TRIPLE-buffered LDS (BK=32, 48KB), depth-2 prefetch with
// counted vmcnt and ONE s_barrier per K-step (r2's barrier count, without
// its vmcnt(0) drain). Step s:
//   s_waitcnt vmcnt(4)   <- stage(s) landed; stage(s+1) stays in flight
//   s_barrier            <- all waves have stage(s); all done reading
//                           buf[(s+2)%3] (they read it in step s-1 and
//                           their lgkmcnt-ordered MFMAs preceded barrier)
//   issue stage(s+2) -> buf[(s+2)%3]
//   ds_read buf[s%3] frags ; 16x MFMA
// Last step peeled with vmcnt(0) (only 4 loads outstanding there).
// XCD-bijective block swizzle (all grids %8==0): FETCH 101->17 MB (r2).
// EPI: 0 = +bias, *scale on Q cols (col0<256), bf16 store   (qkv)
//      1 = +bias, scatter via map, +res, fp32               (proj)
//      2 = +bias, exact GELU (fast erf), bf16 store         (fc1)
//      3 = +bias, +res in place, fp32                       (fc2)
template<int EPI>
__global__ __launch_bounds__(256) void mfma_gemm(
        const unsigned short* __restrict__ A, const unsigned short* __restrict__ B,
        const float* __restrict__ bias, const float* __restrict__ res,
        void* __restrict__ Cout, int M, int N, int K) {
    __shared__ __attribute__((aligned(16))) unsigned short Asm[3][128 * 32];
    __shared__ __attribute__((aligned(16))) unsigned short Bsm[3][128 * 32];
    int tid = threadIdx.x;
    int wave = tid >> 6, lane = tid & 63;

    // XCD-aware bijective swizzle
    int nwg = gridDim.x * gridDim.y;
    int bid = blockIdx.y * gridDim.x + blockIdx.x;
    int swz = (bid & 7) * (nwg >> 3) + (bid >> 3);
    int bx = swz % gridDim.x, by = swz / gridDim.x;

    int row0 = by * 128, col0 = bx * 128;
    int wr = (wave >> 1) * 64;
    int wc = (wave & 1) * 64;

    f32x4 acc[4][4] = {};

    // staging: thread tid -> LDS linear offset tid*16B = row (tid>>2), chunk (tid&3)
    int sr = tid >> 2;
    int sk = (tid & 3) * 8;
    const unsigned short* Ag0 = A + (size_t)(row0 + sr) * K + sk;
    const unsigned short* Ag1 = A + (size_t)(row0 + 64 + sr) * K + sk;
    const unsigned short* Bg0 = B + (size_t)(col0 + sr) * K + sk;
    const unsigned short* Bg1 = B + (size_t)(col0 + 64 + sr) * K + sk;
    int loff = tid * 8;

    int fm = lane & 15, fq = lane >> 4;
    int fks = fq * 8;

    int nk = K >> 5;

    // prologue: stage K-tiles 0,1 into buffers 0,1 (8 loads in flight)
    {
        gll16(Ag0, &Asm[0][loff]);
        gll16(Ag1, &Asm[0][loff + 2048]);
        gll16(Bg0, &Bsm[0][loff]);
        gll16(Bg1, &Bsm[0][loff + 2048]);
        gll16(Ag0 + 32, &Asm[1][loff]);
        gll16(Ag1 + 32, &Asm[1][loff + 2048]);
        gll16(Bg0 + 32, &Bsm[1][loff]);
        gll16(Bg1 + 32, &Bsm[1][loff + 2048]);
    }

    int cur = 0, nxt = 2;   // buf indices: read cur = s%3, write nxt = (s+2)%3
    for (int s = 0; s < nk - 1; ++s) {
        // stage(s) landed (oldest 4 of the ≤8 outstanding); stage(s+1) in flight
        asm volatile("s_waitcnt vmcnt(4)" ::: "memory");
        __builtin_amdgcn_s_barrier();
        if (s + 2 < nk) {                       // WAR-safe: last read of buf[nxt]
            int k0 = (s + 2) << 5;              // was step s-1, sealed by barrier
            gll16(Ag0 + k0, &Asm[nxt][loff]);
            gll16(Ag1 + k0, &Asm[nxt][loff + 2048]);
            gll16(Bg0 + k0, &Bsm[nxt][loff]);
            gll16(Bg1 + k0, &Bsm[nxt][loff + 2048]);
        }
        short8 af[4], bfr[4];
#pragma unroll
        for (int t4 = 0; t4 < 4; ++t4) {
            af[t4]  = *(const short8*)&Asm[cur][(wr + t4 * 16 + fm) * 32 + fks];
            bfr[t4] = *(const short8*)&Bsm[cur][(wc + t4 * 16 + fm) * 32 + fks];
        }
#pragma unroll
        for (int i = 0; i < 4; ++i)
#pragma unroll
            for (int j = 0; j < 4; ++j)
                acc[i][j] = __builtin_amdgcn_mfma_f32_16x16x32_bf16(
                    af[i], bfr[j], acc[i][j], 0, 0, 0);
        cur = (cur == 2) ? 0 : cur + 1;
        nxt = (nxt == 2) ? 0 : nxt + 1;
    }
    {   // peeled last step: only its own 4 loads outstanding -> full drain
        asm volatile("s_waitcnt vmcnt(0)" ::: "memory");
        __builtin_amdgcn_s_barrier();
        short8 af[4], bfr[4];
#pragma unroll
        for (int t4 = 0; t4 < 4; ++t4) {
            af[t4]  = *(const short8*)&Asm[cur][(wr + t4 * 16 + fm) * 32 + fks];
            bfr[t4] = *(const short8*)&Bsm[cur][(wc + t4 * 16 + fm) * 32 + fks];
        }
#pragma unroll
        for (int i = 0; i < 4; ++i)
#pragma unroll
            for (int j = 0; j < 4; ++j)
                acc[i][j] = __builtin_amdgcn_mfma_f32_16x16x32_bf16(
                    af[i], bfr[j], acc[i][j], 0, 0, 0);
    }

    int crow0 = row0 + wr + (lane >> 4) * 4;
    int ccol0 = col0 + wc + (lane & 15);
    float bj[4];
#pragma unroll
    for (int j = 0; j < 4; ++j) bj[j] = bias[ccol0 + j * 16];

    if (EPI == 0) {
        unsigned short* C = (unsigned short*)Cout;
        float mul = (col0 < 256) ? 0.17677669529663687f : 1.f;  // scale Q
#pragma unroll
        for (int i = 0; i < 4; ++i)
#pragma unroll
            for (int v = 0; v < 4; ++v) {
                size_t base = (size_t)(crow0 + i * 16 + v) * N + ccol0;
#pragma unroll
                for (int j = 0; j < 4; ++j)
                    C[base + j * 16] = f2bf((acc[i][j][v] + bj[j]) * mul);
            }
    } else if (EPI == 1) {
        float* C = (float*)Cout;
#pragma unroll
        for (int i = 0; i < 4; ++i)
#pragma unroll
            for (int v = 0; v < 4; ++v) {
                int r = crow0 + i * 16 + v;
                size_t base = (size_t)win_token_to_flat(r) * C_DIM + ccol0;
#pragma unroll
                for (int j = 0; j < 4; ++j)
                    C[base + j * 16] = res[base + j * 16] + acc[i][j][v] + bj[j];
            }
    } else if (EPI == 2) {
        unsigned short* C = (unsigned short*)Cout;
#pragma unroll
        for (int i = 0; i < 4; ++i)
#pragma unroll
            for (int v = 0; v < 4; ++v) {
                size_t base = (size_t)(crow0 + i * 16 + v) * N + ccol0;
#pragma unroll
                for (int j = 0; j < 4; ++j)
                    C[base + j * 16] = f2bf(gelu_exact(acc[i][j][v] + bj[j]));
            }
    } else {
        float* C = (float*)Cout;
#pragma unroll
        for (int i = 0; i < 4; ++i)
#pragma unroll
            for (int v = 0; v < 4; ++v) {
                size_t base = (size_t)(crow0 + i * 16 + v) * N + ccol0;
#pragma unroll
                for (int j = 0; j < 4; ++j)
                    C[base + j * 16] = res[base + j * 16] + acc[i][j][v] + bj[j];
            }
    }
}

// MFMA windowed attention: one block per (window, head), 4 waves.
// N=98 padded to 112 (7 row-strips of 16). Per strip (owned by one wave):
//   S = Q K^T (7 MFMA, A/B frags direct from global, row-clamped)
//   + bm table, row softmax (16-lane shfl_xor), P -> LDS (C->A layout),
//   O = P V via 8 MFMA against LDS-transposed V, *1/rowsum at store.
// qkv is bf16, Q pre-scaled by 32^-0.5 in the qkv GEMM epilogue.
__global__ __launch_bounds__(256) void attn_mfma_kernel(
        const unsigned short* __restrict__ qkv, const float* __restrict__ bm,
        unsigned short* __restrict__ out) {
    __shared__ __attribute__((aligned(16))) unsigned short Vt[32][136];
    __shared__ __attribute__((aligned(16))) unsigned short Pw[4][16][136];
    int blk = blockIdx.x;
    int g = blk >> 3, head = blk & 7;
    int tid = threadIdx.x, wave = tid >> 6, lane = tid & 63;

    // zero Vt token-pad cols [98,128) (P pad cols are exact 0, need finite V there)
    for (int i = tid; i < 32 * 30; i += 256) {
        int d = i / 30, c = 98 + (i - d * 30);
        Vt[d][c] = 0;
    }
    // stage V_h transposed: Vt[d][token], coalesced global reads
    const unsigned short* vbase = qkv + (size_t)g * 98 * 768 + 512 + head * 32;
    for (int i = tid; i < 98 * 16; i += 256) {
        int n = i >> 4, dp = i & 15;
        unsigned int val = *(const unsigned int*)(vbase + (size_t)n * 768 + dp * 2);
        Vt[dp * 2][n]     = (unsigned short)val;
        Vt[dp * 2 + 1][n] = (unsigned short)(val >> 16);
    }
    // zero per-wave P k-pad cols [112,128) (read by last PV k-step)
    {
        int m = lane >> 2, c = 112 + (lane & 3) * 4;
        *(unsigned long long*)&Pw[wave][m][c] = 0ULL;
    }
    __syncthreads();

    const unsigned short* qbase = qkv + (size_t)g * 98 * 768 + head * 32;
    const unsigned short* kbase = qbase + 256;
    int rem = g & 255;
    int cls = (((rem >> 6) == 3) << 2) | (((((rem >> 3) & 7)) == 7) << 1) | ((rem & 7) == 7);
    const float* bmh = bm + (size_t)(cls * 8 + head) * 112 * 112;

    int fm = lane & 15, fq = lane >> 4;
    int fk = fq * 8;
    unsigned short* obase = out + (size_t)g * 98 * 256 + head * 32;

    for (int s = wave; s < 7; s += 4) {
        int m0 = s * 16;
        int arow = m0 + fm; if (arow > 97) arow = 97;   // clamp pad rows (finite garbage)
        short8 af = *(const short8*)(qbase + (size_t)arow * 768 + fk);
        f32x4 S[7];
        f32x4 z = {0.f, 0.f, 0.f, 0.f};
#pragma unroll
        for (int j = 0; j < 7; ++j) {
            int krow = j * 16 + fm; if (krow > 97) krow = 97;
            short8 kf = *(const short8*)(kbase + (size_t)krow * 768 + fk);
            S[j] = __builtin_amdgcn_mfma_f32_16x16x32_bf16(af, kf, z, 0, 0, 0);
        }
        // + bias/mask table (pad cols get -1e30 -> exp 0)
        const float* bmrow = bmh + (m0 + fq * 4) * 112 + fm;
#pragma unroll
        for (int j = 0; j < 7; ++j)
#pragma unroll
            for (int v = 0; v < 4; ++v)
                S[j][v] += bmrow[v * 112 + j * 16];
        // row softmax: rows live in 16-lane col groups (lane&15), 4 rows/lane (v)
        float inv[4];
#pragma unroll
        for (int v = 0; v < 4; ++v) {
            float m_ = S[0][v];
#pragma unroll
            for (int j = 1; j < 7; ++j) m_ = fmaxf(m_, S[j][v]);
#pragma unroll
            for (int o = 1; o < 16; o <<= 1) m_ = fmaxf(m_, __shfl_xor(m_, o, 64));
            float t = 0.f;
#pragma unroll
            for (int j = 0; j < 7; ++j) { S[j][v] = __expf(S[j][v] - m_); t += S[j][v]; }
#pragma unroll
            for (int o = 1; o < 16; o <<= 1) t += __shfl_xor(t, o, 64);
            inv[v] = 1.f / t;   // applied at output store (PV is linear)
        }
        // P: C-layout -> A-layout via per-wave LDS (same-wave DS ordering, no barrier)
#pragma unroll
        for (int j = 0; j < 7; ++j)
#pragma unroll
            for (int v = 0; v < 4; ++v)
                Pw[wave][fq * 4 + v][j * 16 + fm] = f2bf(S[j][v]);
        // O = P @ V
        f32x4 O0 = {0.f, 0.f, 0.f, 0.f}, O1 = {0.f, 0.f, 0.f, 0.f};
#pragma unroll
        for (int ks = 0; ks < 4; ++ks) {
            short8 pf = *(const short8*)&Pw[wave][fm][ks * 32 + fk];
            short8 v0 = *(const short8*)&Vt[fm][ks * 32 + fk];
            short8 v1 = *(const short8*)&Vt[16 + fm][ks * 32 + fk];
            O0 = __builtin_amdgcn_mfma_f32_16x16x32_bf16(pf, v0, O0, 0, 0, 0);
            O1 = __builtin_amdgcn_mfma_f32_16x16x32_bf16(pf, v1, O1, 0, 0, 0);
        }
#pragma unroll
        for (int v = 0; v < 4; ++v) {
            int row = m0 + fq * 4 + v;
            if (row < 98) {
                obase[(size_t)row * 256 + fm]      = f2bf(O0[v] * inv[v]);
                obase[(size_t)row * 256 + 16 + fm] = f2bf(O1[v] * inv[v]);
            }
        }
    }
}

extern "C" void kernel_launch(void* const* d_in, const int* in_sizes, int n_in,
                              void* d_out, int out_size, void* d_ws, size_t ws_size,
                              hipStream_t stream) {
    const float* x     = (const float*)d_in[0];
    const float* n1w   = (const float*)d_in[1];
    const float* n1b   = (const float*)d_in[2];
    const float* qkvw  = (const float*)d_in[3];
    const float* qkvb  = (const float*)d_in[4];
    const float* projw = (const float*)d_in[5];
    const float* projb = (const float*)d_in[6];
    const float* rpe   = (const float*)d_in[7];
    const float* n2w   = (const float*)d_in[8];
    const float* n2b   = (const float*)d_in[9];
    const float* fc1w  = (const float*)d_in[10];
    const float* fc1b  = (const float*)d_in[11];
    const float* fc2w  = (const float*)d_in[12];
    const float* fc2b  = (const float*)d_in[13];
    float* out = (float*)d_out;

    // workspace layout
    unsigned short* wqkv  = (unsigned short*)d_ws;            // 768*256 bf16
    unsigned short* wproj = wqkv + 768 * 256;                 // 256*256
    unsigned short* wfc1  = wproj + 256 * 256;                // 1024*256
    unsigned short* wfc2  = wfc1 + 1024 * 256;                // 256*1024
    float* bm = (float*)(wfc2 + 256 * 1024);                  // 8*8*112*112 fp32
    unsigned short* actA  = (unsigned short*)(bm + 8 * 8 * 112 * 112); // TOKENS*256 bf16
    unsigned short* attnO = actA + (size_t)TOKENS * 256;      // TOKENS*256 bf16
    unsigned short* qkv_bf = attnO + (size_t)TOKENS * 256;    // TOKENS*768 bf16
    unsigned short* fc1o = qkv_bf;                            // TOKENS*1024 bf16 (aliases dead qkv)

    // 0. bias/mask tables + weight casts
    bm_kernel<<<8 * 8 * 112 * 112 / 256, 256, 0, stream>>>(rpe, bm);
    cvt_kernel<<<(768 * 256 + 255) / 256, 256, 0, stream>>>(qkvw, wqkv, 768 * 256);
    cvt_kernel<<<(256 * 256 + 255) / 256, 256, 0, stream>>>(projw, wproj, 256 * 256);
    cvt_kernel<<<(1024 * 256 + 255) / 256, 256, 0, stream>>>(fc1w, wfc1, 1024 * 256);
    cvt_kernel<<<(256 * 1024 + 255) / 256, 256, 0, stream>>>(fc2w, wfc2, 256 * 1024);

    // 1. LN1 + roll + window partition (gather), bf16 out
    ln_kernel<true><<<TOKENS / 4, 256, 0, stream>>>(x, n1w, n1b, actA);
    // 2. QKV projection -> bf16, Q pre-scaled
    mfma_gemm<0><<<dim3(768 / 128, TOKENS / 128), 256, 0, stream>>>(
        actA, wqkv, qkvb, nullptr, qkv_bf, TOKENS, 768, 256);
    // 3. MFMA windowed attention -> bf16
    attn_mfma_kernel<<<NWIN * 8, 256, 0, stream>>>(qkv_bf, bm, attnO);
    // 4. proj + window reverse + roll back + residual -> d_out (x1, fp32)
    mfma_gemm<1><<<dim3(256 / 128, TOKENS / 128), 256, 0, stream>>>(
        attnO, wproj, projb, x, out, TOKENS, 256, 256);
    // 5. LN2 -> bf16
    ln_kernel<false><<<TOKENS / 4, 256, 0, stream>>>(out, n2w, n2b, actA);
    // 6. FC1 + GELU -> bf16 (aliases dead qkv buffer)
    mfma_gemm<2><<<dim3(1024 / 128, TOKENS / 128), 256, 0, stream>>>(
        actA, wfc1, fc1b, nullptr, fc1o, TOKENS, 1024, 256);
    // 7. FC2 + residual (in place on d_out)
    mfma_gemm<3><<<dim3(256 / 128, TOKENS / 128), 256, 0, stream>>>(
        fc1o, wfc2, fc2b, out, out, TOKENS, 256, 1024);
}

// Round 6
// 382.468 us; speedup vs baseline: 1.4152x; 1.0865x over previous
//
#include <hip/hip_runtime.h>
#include <math.h>

// Problem constants (fixed by setup_inputs)
#define TOKENS 50176   // B*T*H*W = 2*8*56*56
#define NWIN   512     // total windows = B * 256
#define C_DIM  256

typedef __attribute__((ext_vector_type(8))) short short8;
typedef __attribute__((ext_vector_type(4))) float f32x4;

// float -> bf16 with round-to-nearest-even
__device__ __forceinline__ unsigned short f2bf(float f) {
    unsigned int u = __builtin_bit_cast(unsigned int, f);
    u += 0x7fffu + ((u >> 16) & 1);
    return (unsigned short)(u >> 16);
}

// async global->LDS, 16B per lane (global_load_lds_dwordx4)
__device__ __forceinline__ void gll16(const void* g, void* l) {
    __builtin_amdgcn_global_load_lds(
        (const __attribute__((address_space(1))) unsigned int*)g,
        (__attribute__((address_space(3))) unsigned int*)l, 16, 0, 0);
}

// exact-enough GELU: Abramowitz-Stegun 7.1.26 erf (|eps|<=1.5e-7) via
// hardware v_rcp_f32 + v_exp_f32. ~13 VALU ops, branch-free. Replacing
// libm erff dropped FC1 VALUBusy 47.6% -> 10.2% (measured r3).
__device__ __forceinline__ float gelu_exact(float v) {
    float z  = v * 0.70710678118654752f;
    float az = fabsf(z);
    float t  = __builtin_amdgcn_rcpf(1.f + 0.3275911f * az);
    float p  = ((((1.061405429f * t - 1.453152027f) * t + 1.421413741f) * t
                 - 0.284496736f) * t + 0.254829592f) * t;
    float er = 1.f - p * __expf(-az * az);
    er = (z < 0.f) ? -er : er;
    return 0.5f * v * (1.f + er);
}

// Map a window-ordered token index u -> flat (b,t,h,w) index.
__device__ __forceinline__ int win_token_to_flat(int u) {
    int g = u / 98;
    int n = u - g * 98;
    int bb  = g >> 8;
    int rem = g & 255;
    int tb = rem >> 6, hb = (rem >> 3) & 7, wb = rem & 7;
    int dt = n / 49;
    int r2 = n - dt * 49;
    int dh = r2 / 7, dw = r2 - dh * 7;
    int t = tb * 2 + dt, h = hb * 7 + dh, w = wb * 7 + dw;
    int ts = (t + 1) & 7;
    int hs = h + 3; if (hs >= 56) hs -= 56;
    int wsx = w + 3; if (wsx >= 56) wsx -= 56;
    return ((bb * 8 + ts) * 56 + hs) * 56 + wsx;
}

// fused elementwise fp32 -> bf16 for all 4 weight matrices (one launch)
__global__ __launch_bounds__(256) void cvt_all_kernel(
        const float* __restrict__ s0, const float* __restrict__ s1,
        const float* __restrict__ s2, const float* __restrict__ s3,
        unsigned short* __restrict__ d0, unsigned short* __restrict__ d1,
        unsigned short* __restrict__ d2, unsigned short* __restrict__ d3) {
    int i = blockIdx.x * 256 + threadIdx.x;       // total 786432 exact
    if (i < 196608)      d0[i] = f2bf(s0[i]);                       // qkv_w
    else if (i < 262144) d1[i - 196608] = f2bf(s1[i - 196608]);     // proj_w
    else if (i < 524288) d2[i - 262144] = f2bf(s2[i - 262144]);     // fc1_w
    else                 d3[i - 524288] = f2bf(s3[i - 524288]);     // fc2_w
}

// Precompute combined rel-pos bias + shift mask tables:
// bm[cls 8][head 8][row 112][col 112] fp32. cls bits: (tb==3)<<2 | (hb==7)<<1 | (wb==7).
__global__ __launch_bounds__(256) void bm_kernel(
        const float* __restrict__ rpe, float* __restrict__ bm) {
    int i = blockIdx.x * 256 + threadIdx.x;   // 8*8*112*112 = 802816 exact
    int c  = i % 112;
    int t1 = i / 112;
    int r  = t1 % 112;
    int t2 = t1 / 112;
    int head = t2 & 7;
    int cls  = t2 >> 3;
    float val;
    if (c >= 98) {
        val = -1e30f;
    } else if (r >= 98) {
        val = 0.f;
    } else {
        int dt = r / 49, rr = r - dt * 49, dh = rr / 7, dw = rr - dh * 7;
        int dt2 = c / 49, cc = c - dt2 * 49, dh2 = cc / 7, dw2 = cc - dh2 * 7;
        int rt  = (cls & 4) ? (dt  == 0 ? 1 : 2) : 0;
        int rh  = (cls & 2) ? (dh  <  4 ? 1 : 2) : 0;
        int rw  = (cls & 1) ? (dw  <  4 ? 1 : 2) : 0;
        int rt2 = (cls & 4) ? (dt2 == 0 ? 1 : 2) : 0;
        int rh2 = (cls & 2) ? (dh2 <  4 ? 1 : 2) : 0;
        int rw2 = (cls & 1) ? (dw2 <  4 ? 1 : 2) : 0;
        int reg1 = rt * 9 + rh * 3 + rw, reg2 = rt2 * 9 + rh2 * 3 + rw2;
        int idx = (dt - dt2 + 1) * 169 + (dh - dh2 + 6) * 13 + (dw - dw2 + 6);
        val = rpe[idx * 8 + head] + ((reg1 == reg2) ? 0.f : -100.f);
    }
    bm[i] = val;
}

// LayerNorm over C=256, one wave per token, bf16 output.
template<bool GATHER>
__global__ __launch_bounds__(256) void ln_kernel(
        const float* __restrict__ x, const float* __restrict__ w,
        const float* __restrict__ b, unsigned short* __restrict__ out) {
    int token = blockIdx.x * 4 + (threadIdx.x >> 6);
    int lane  = threadIdx.x & 63;
    size_t so = GATHER ? (size_t)win_token_to_flat(token) * C_DIM
                       : (size_t)token * C_DIM;
    const float* src = x + so;
    float v[4];
    float sum = 0.f;
#pragma unroll
    for (int j = 0; j < 4; ++j) { v[j] = src[lane + 64 * j]; sum += v[j]; }
#pragma unroll
    for (int o = 32; o > 0; o >>= 1) sum += __shfl_xor(sum, o, 64);
    float mu = sum * (1.f / 256.f);
    float var = 0.f;
#pragma unroll
    for (int j = 0; j < 4; ++j) { float d = v[j] - mu; var += d * d; }
#pragma unroll
    for (int o = 32; o > 0; o >>= 1) var += __shfl_xor(var, o, 64);
    float rstd = rsqrtf(var * (1.f / 256.f) + 1e-5f);
    unsigned short* dst = out + (size_t)token * C_DIM;
#pragma unroll
    for (int j = 0; j < 4; ++j) {
        int c = lane + 64 * j;
        dst[c] = f2bf((v[j] - mu) * rstd * w[c] + b[c]);
    }
}

// bf16 MFMA GEMM: C(MxN) = A(MxK) @ B(NxK)^T.
// K-loop: r2 structure (best measured): double-buffered LDS (BK=32, 32KB),
// ONE __syncthreads per K-step, next tile's global_load_lds issued right
// after the barrier. XCD-bijective block swizzle (FETCH 101->17MB, r2).
// Epilogue (new, r6): LDS round-trip for fully-coalesced global traffic.
// The direct fragment-order store was four 32B (bf16) / 64B (fp32)
// segments per instruction -> ~half of every HBM write burst wasted; the
// epilogue (up to 103MB/kernel) dominated all four GEMMs at ~50us.
//   bf16 out: stage 128x128 bf16 tile in smem, 8 thread-linear short8
//             store passes (1KB/wave/instr).
//   fp32 out: stage 64x128 fp32 half-tiles, 4 thr/row x 32 contiguous
//             cols: float4 res-read + add + store (512B/row bursts).
// EPI: 0 = +bias, *scale on Q cols (col0<256), bf16   (qkv)
//      1 = +bias, scatter rows via map, +res, fp32    (proj)
//      2 = +bias, fast-exact GELU, bf16               (fc1)
//      3 = +bias, +res, fp32                          (fc2)
template<int EPI>
__global__ __launch_bounds__(256) void mfma_gemm(
        const unsigned short* __restrict__ A, const unsigned short* __restrict__ B,
        const float* __restrict__ bias, const float* __restrict__ res,
        void* __restrict__ Cout, int M, int N, int K) {
    __shared__ __attribute__((aligned(16))) unsigned short smem[4][128 * 32]; // 32KB
#define ASMB(b) (smem[(b)])
#define BSMB(b) (smem[2 + (b)])
    int tid = threadIdx.x;
    int wave = tid >> 6, lane = tid & 63;

    // XCD-aware bijective swizzle (all grids here are %8==0)
    int nwg = gridDim.x * gridDim.y;
    int bid = blockIdx.y * gridDim.x + blockIdx.x;
    int swz = (bid & 7) * (nwg >> 3) + (bid >> 3);
    int bx = swz % gridDim.x, by = swz / gridDim.x;

    int row0 = by * 128, col0 = bx * 128;
    int wr = (wave >> 1) * 64;
    int wc = (wave & 1) * 64;

    f32x4 acc[4][4] = {};

    int sr = tid >> 2;
    int sk = (tid & 3) * 8;
    const unsigned short* Ag0 = A + (size_t)(row0 + sr) * K + sk;
    const unsigned short* Ag1 = A + (size_t)(row0 + 64 + sr) * K + sk;
    const unsigned short* Bg0 = B + (size_t)(col0 + sr) * K + sk;
    const unsigned short* Bg1 = B + (size_t)(col0 + 64 + sr) * K + sk;
    int loff = tid * 8;

    int fm = lane & 15, fq = lane >> 4;
    int fks = fq * 8;

    // prologue: stage K-tile 0 into buffer 0
    gll16(Ag0, &ASMB(0)[loff]);
    gll16(Ag1, &ASMB(0)[loff + 2048]);
    gll16(Bg0, &BSMB(0)[loff]);
    gll16(Bg1, &BSMB(0)[loff + 2048]);

    int nk = K >> 5;
    for (int s = 0; s < nk; ++s) {
        int cur = s & 1;
        __syncthreads();   // drains vmcnt: buf[cur] staged; buf[cur^1] reads done
        if (s + 1 < nk) {
            int k0 = (s + 1) << 5;
            gll16(Ag0 + k0, &ASMB(cur ^ 1)[loff]);
            gll16(Ag1 + k0, &ASMB(cur ^ 1)[loff + 2048]);
            gll16(Bg0 + k0, &BSMB(cur ^ 1)[loff]);
            gll16(Bg1 + k0, &BSMB(cur ^ 1)[loff + 2048]);
        }
        short8 af[4], bfr[4];
#pragma unroll
        for (int t4 = 0; t4 < 4; ++t4) {
            af[t4]  = *(const short8*)&ASMB(cur)[(wr + t4 * 16 + fm) * 32 + fks];
            bfr[t4] = *(const short8*)&BSMB(cur)[(wc + t4 * 16 + fm) * 32 + fks];
        }
#pragma unroll
        for (int i = 0; i < 4; ++i)
#pragma unroll
            for (int j = 0; j < 4; ++j)
                acc[i][j] = __builtin_amdgcn_mfma_f32_16x16x32_bf16(
                    af[i], bfr[j], acc[i][j], 0, 0, 0);
    }

    int ccol0 = col0 + wc + fm;
    float bj[4];
#pragma unroll
    for (int j = 0; j < 4; ++j) bj[j] = bias[ccol0 + j * 16];

    __syncthreads();   // K-loop LDS reads done everywhere; reuse smem

    if (EPI == 0 || EPI == 2) {
        // ---- bf16 output: stage full 128x128 bf16 tile, coalesced stores
        unsigned short* Ls = &smem[0][0];          // [128][128] ushort = 32KB
        float mul = (EPI == 0 && col0 < 256) ? 0.17677669529663687f : 1.f;
#pragma unroll
        for (int i = 0; i < 4; ++i)
#pragma unroll
            for (int v = 0; v < 4; ++v) {
                int lr = wr + i * 16 + fq * 4 + v;
#pragma unroll
                for (int j = 0; j < 4; ++j) {
                    float val = acc[i][j][v] + bj[j];
                    val = (EPI == 2) ? gelu_exact(val) : val * mul;
                    Ls[lr * 128 + wc + j * 16 + fm] = f2bf(val);
                }
            }
        __syncthreads();
        unsigned short* C = (unsigned short*)Cout;
#pragma unroll
        for (int p = 0; p < 8; ++p) {
            int lin = p * 2048 + tid * 8;
            int lr = lin >> 7, lc = lin & 127;
            *(short8*)(C + (size_t)(row0 + lr) * N + col0 + lc) =
                *(const short8*)&Ls[lin];
        }
    } else {
        // ---- fp32 output (+res): two 64x128 fp32 half-tiles
        float* fs = (float*)&smem[0][0];           // [64][128] float = 32KB
        float* C = (float*)Cout;
#pragma unroll
        for (int h = 0; h < 2; ++h) {
            if (h) __syncthreads();                // pass-0 readers done
            if (wr == h * 64) {
#pragma unroll
                for (int i = 0; i < 4; ++i)
#pragma unroll
                    for (int v = 0; v < 4; ++v) {
                        int lr = i * 16 + fq * 4 + v;
#pragma unroll
                        for (int j = 0; j < 4; ++j)
                            fs[lr * 128 + wc + j * 16 + fm] = acc[i][j][v] + bj[j];
                    }
            }
            __syncthreads();
            int tr = tid >> 2, tcb = (tid & 3) * 32;
            int grow = row0 + h * 64 + tr;
            size_t gbase = (EPI == 1)
                ? (size_t)win_token_to_flat(grow) * C_DIM + col0 + tcb
                : (size_t)grow * N + col0 + tcb;
            const float* rs = res + gbase;
            float* Cp = C + gbase;
            const float* ls = &fs[tr * 128 + tcb];
#pragma unroll
            for (int q = 0; q < 8; ++q) {
                f32x4 r = *(const f32x4*)(rs + q * 4);
                f32x4 a = *(const f32x4*)(ls + q * 4);
                r.x += a.x; r.y += a.y; r.z += a.z; r.w += a.w;
                *(f32x4*)(Cp + q * 4) = r;
            }
        }
    }
#undef ASMB
#undef BSMB
}

// MFMA windowed attention: one block per (window, head), 4 waves.
__global__ __launch_bounds__(256) void attn_mfma_kernel(
        const unsigned short* __restrict__ qkv, const float* __restrict__ bm,
        unsigned short* __restrict__ out) {
    __shared__ __attribute__((aligned(16))) unsigned short Vt[32][136];
    __shared__ __attribute__((aligned(16))) unsigned short Pw[4][16][136];
    int blk = blockIdx.x;
    int g = blk >> 3, head = blk & 7;
    int tid = threadIdx.x, wave = tid >> 6, lane = tid & 63;

    // zero Vt token-pad cols [98,128)
    for (int i = tid; i < 32 * 30; i += 256) {
        int d = i / 30, c = 98 + (i - d * 30);
        Vt[d][c] = 0;
    }
    // stage V_h transposed: Vt[d][token], coalesced global reads
    const unsigned short* vbase = qkv + (size_t)g * 98 * 768 + 512 + head * 32;
    for (int i = tid; i < 98 * 16; i += 256) {
        int n = i >> 4, dp = i & 15;
        unsigned int val = *(const unsigned int*)(vbase + (size_t)n * 768 + dp * 2);
        Vt[dp * 2][n]     = (unsigned short)val;
        Vt[dp * 2 + 1][n] = (unsigned short)(val >> 16);
    }
    // zero per-wave P k-pad cols [112,128)
    {
        int m = lane >> 2, c = 112 + (lane & 3) * 4;
        *(unsigned long long*)&Pw[wave][m][c] = 0ULL;
    }
    __syncthreads();

    const unsigned short* qbase = qkv + (size_t)g * 98 * 768 + head * 32;
    const unsigned short* kbase = qbase + 256;
    int rem = g & 255;
    int cls = (((rem >> 6) == 3) << 2) | (((((rem >> 3) & 7)) == 7) << 1) | ((rem & 7) == 7);
    const float* bmh = bm + (size_t)(cls * 8 + head) * 112 * 112;

    int fm = lane & 15, fq = lane >> 4;
    int fk = fq * 8;
    unsigned short* obase = out + (size_t)g * 98 * 256 + head * 32;

    for (int s = wave; s < 7; s += 4) {
        int m0 = s * 16;
        int arow = m0 + fm; if (arow > 97) arow = 97;
        short8 af = *(const short8*)(qbase + (size_t)arow * 768 + fk);
        f32x4 S[7];
        f32x4 z = {0.f, 0.f, 0.f, 0.f};
#pragma unroll
        for (int j = 0; j < 7; ++j) {
            int krow = j * 16 + fm; if (krow > 97) krow = 97;
            short8 kf = *(const short8*)(kbase + (size_t)krow * 768 + fk);
            S[j] = __builtin_amdgcn_mfma_f32_16x16x32_bf16(af, kf, z, 0, 0, 0);
        }
        const float* bmrow = bmh + (m0 + fq * 4) * 112 + fm;
#pragma unroll
        for (int j = 0; j < 7; ++j)
#pragma unroll
            for (int v = 0; v < 4; ++v)
                S[j][v] += bmrow[v * 112 + j * 16];
        float inv[4];
#pragma unroll
        for (int v = 0; v < 4; ++v) {
            float m_ = S[0][v];
#pragma unroll
            for (int j = 1; j < 7; ++j) m_ = fmaxf(m_, S[j][v]);
#pragma unroll
            for (int o = 1; o < 16; o <<= 1) m_ = fmaxf(m_, __shfl_xor(m_, o, 64));
            float t = 0.f;
#pragma unroll
            for (int j = 0; j < 7; ++j) { S[j][v] = __expf(S[j][v] - m_); t += S[j][v]; }
#pragma unroll
            for (int o = 1; o < 16; o <<= 1) t += __shfl_xor(t, o, 64);
            inv[v] = 1.f / t;
        }
#pragma unroll
        for (int j = 0; j < 7; ++j)
#pragma unroll
            for (int v = 0; v < 4; ++v)
                Pw[wave][fq * 4 + v][j * 16 + fm] = f2bf(S[j][v]);
        f32x4 O0 = {0.f, 0.f, 0.f, 0.f}, O1 = {0.f, 0.f, 0.f, 0.f};
#pragma unroll
        for (int ks = 0; ks < 4; ++ks) {
            short8 pf = *(const short8*)&Pw[wave][fm][ks * 32 + fk];
            short8 v0 = *(const short8*)&Vt[fm][ks * 32 + fk];
            short8 v1 = *(const short8*)&Vt[16 + fm][ks * 32 + fk];
            O0 = __builtin_amdgcn_mfma_f32_16x16x32_bf16(pf, v0, O0, 0, 0, 0);
            O1 = __builtin_amdgcn_mfma_f32_16x16x32_bf16(pf, v1, O1, 0, 0, 0);
        }
#pragma unroll
        for (int v = 0; v < 4; ++v) {
            int row = m0 + fq * 4 + v;
            if (row < 98) {
                obase[(size_t)row * 256 + fm]      = f2bf(O0[v] * inv[v]);
                obase[(size_t)row * 256 + 16 + fm] = f2bf(O1[v] * inv[v]);
            }
        }
    }
}

extern "C" void kernel_launch(void* const* d_in, const int* in_sizes, int n_in,
                              void* d_out, int out_size, void* d_ws, size_t ws_size,
                              hipStream_t stream) {
    const float* x     = (const float*)d_in[0];
    const float* n1w   = (const float*)d_in[1];
    const float* n1b   = (const float*)d_in[2];
    const float* qkvw  = (const float*)d_in[3];
    const float* qkvb  = (const float*)d_in[4];
    const float* projw = (const float*)d_in[5];
    const float* projb = (const float*)d_in[6];
    const float* rpe   = (const float*)d_in[7];
    const float* n2w   = (const float*)d_in[8];
    const float* n2b   = (const float*)d_in[9];
    const float* fc1w  = (const float*)d_in[10];
    const float* fc1b  = (const float*)d_in[11];
    const float* fc2w  = (const float*)d_in[12];
    const float* fc2b  = (const float*)d_in[13];
    float* out = (float*)d_out;

    // workspace layout
    unsigned short* wqkv  = (unsigned short*)d_ws;            // 768*256 bf16
    unsigned short* wproj = wqkv + 768 * 256;                 // 256*256
    unsigned short* wfc1  = wproj + 256 * 256;                // 1024*256
    unsigned short* wfc2  = wfc1 + 1024 * 256;                // 256*1024
    float* bm = (float*)(wfc2 + 256 * 1024);                  // 8*8*112*112 fp32
    unsigned short* actA  = (unsigned short*)(bm + 8 * 8 * 112 * 112); // TOKENS*256 bf16
    unsigned short* attnO = actA + (size_t)TOKENS * 256;      // TOKENS*256 bf16
    unsigned short* qkv_bf = attnO + (size_t)TOKENS * 256;    // TOKENS*768 bf16
    unsigned short* fc1o = qkv_bf;                            // TOKENS*1024 bf16 (aliases dead qkv)

    // 0. bias/mask tables + weight casts (single fused cast launch)
    bm_kernel<<<8 * 8 * 112 * 112 / 256, 256, 0, stream>>>(rpe, bm);
    cvt_all_kernel<<<786432 / 256, 256, 0, stream>>>(
        qkvw, projw, fc1w, fc2w, wqkv, wproj, wfc1, wfc2);

    // 1. LN1 + roll + window partition (gather), bf16 out
    ln_kernel<true><<<TOKENS / 4, 256, 0, stream>>>(x, n1w, n1b, actA);
    // 2. QKV projection -> bf16, Q pre-scaled
    mfma_gemm<0><<<dim3(768 / 128, TOKENS / 128), 256, 0, stream>>>(
        actA, wqkv, qkvb, nullptr, qkv_bf, TOKENS, 768, 256);
    // 3. MFMA windowed attention -> bf16
    attn_mfma_kernel<<<NWIN * 8, 256, 0, stream>>>(qkv_bf, bm, attnO);
    // 4. proj + window reverse + roll back + residual -> d_out (x1, fp32)
    mfma_gemm<1><<<dim3(256 / 128, TOKENS / 128), 256, 0, stream>>>(
        attnO, wproj, projb, x, out, TOKENS, 256, 256);
    // 5. LN2 -> bf16
    ln_kernel<false><<<TOKENS / 4, 256, 0, stream>>>(out, n2w, n2b, actA);
    // 6. FC1 + GELU -> bf16 (aliases dead qkv buffer)
    mfma_gemm<2><<<dim3(1024 / 128, TOKENS / 128), 256, 0, stream>>>(
        actA, wfc1, fc1b, nullptr, fc1o, TOKENS, 1024, 256);
    // 7. FC2 + residual (in place on d_out)
    mfma_gemm<3><<<dim3(256 / 128, TOKENS / 128), 256, 0, stream>>>(
        fc1o, wfc2, fc2b, out, out, TOKENS, 256, 1024);
}